// Round 1
// 202.253 us; speedup vs baseline: 1.0148x; 1.0148x over previous
//
#include <hip/hip_runtime.h>
#include <hip/hip_bf16.h>

// ---------------------------------------------------------------------------
// NAFNet-like block, MI355X (gfx950). B=2,C=64,H=W=256,DW=128,FFN=128,GRID=8.
// fp32 true inputs + fp32 output; bf16 intermediates; MFMA 16x16x32 bf16.
// R7: dispatch count 6->4. sca_k folded into tail_k (per-block 64x64 matvec
//     from s0, LDS). s0 zeroing folded into prep_k (no memset). XCD-aware
//     grid transpose: uv/oc fastest blockIdx dim so blocks sharing weight
//     tables / halo rows land on the same XCD L2 (T1 mechanism).
// ---------------------------------------------------------------------------

typedef __bf16 bf16x8 __attribute__((ext_vector_type(8)));
typedef float f32x4 __attribute__((ext_vector_type(4)));
typedef unsigned short u16x8 __attribute__((ext_vector_type(8)));

__device__ __forceinline__ float b2f(unsigned short u) {
    union { unsigned int i; float f; } x; x.i = ((unsigned int)u) << 16; return x.f;
}
__device__ __forceinline__ unsigned short f2b(float f) {
    union { float f; unsigned int i; } x; x.f = f;
    unsigned int i = x.i;
    return (unsigned short)((i + 0x7FFFu + ((i >> 16) & 1u)) >> 16);  // RNE
}
__device__ __forceinline__ unsigned int pk2(float a, float b) {
    __hip_bfloat162 h = __float22bfloat162_rn(float2{a, b});  // v_cvt_pk_bf16_f32
    union { __hip_bfloat162 h; unsigned int u; } cv; cv.h = h; return cv.u;
}

// ---------------------------------------------------------------------------
// prep_k: demodulated bf16 weight tables [b][uv][o][c] for conv1/3/4/5.
// Grid 768 = 256(conv1) + 128(conv3,beta) + 256(conv4) + 128(conv5,gamma).
// Also zeroes s0 (block 0) so no separate memset dispatch is needed.
// ---------------------------------------------------------------------------
__global__ __launch_bounds__(256) void prep_k(
    const float* __restrict__ w1, const float* __restrict__ mod1,
    const float* __restrict__ w3, const float* __restrict__ mod3,
    const float* __restrict__ beta,
    const float* __restrict__ w4, const float* __restrict__ mod4,
    const float* __restrict__ w5, const float* __restrict__ mod5,
    const float* __restrict__ gam,
    unsigned short* __restrict__ pw1, unsigned short* __restrict__ pw3,
    unsigned short* __restrict__ pw4, unsigned short* __restrict__ pw5,
    float* __restrict__ s0)
{
    const int tid = threadIdx.x;
    int blk = blockIdx.x;
    if (blk == 0 && tid < 128) s0[tid] = 0.f;   // consumed only by dw_k/tail_k later
    const float* w; const float* mod; const float* rows = nullptr;
    unsigned short* out; int NOUT; int rem;
    if (blk < 256)      { w = w1; mod = mod1; out = pw1; NOUT = 128; rem = blk; }
    else if (blk < 384) { w = w3; mod = mod3; out = pw3; NOUT = 64;  rem = blk - 256; rows = beta; }
    else if (blk < 640) { w = w4; mod = mod4; out = pw4; NOUT = 128; rem = blk - 384; }
    else                { w = w5; mod = mod5; out = pw5; NOUT = 64;  rem = blk - 640; rows = gam; }
    const int b = rem / NOUT, o = rem % NOUT;

    __shared__ float mlds[64 * 68];   // [c][uv], pad 68
    __shared__ float wlsh[64];
    __shared__ float red[4 * 64];
    __shared__ float rs[64];

    const float* mbase = mod + ((size_t)(b * NOUT + o) * 64) * 64;  // [c][uv]
#pragma unroll
    for (int k = 0; k < 4; ++k) {
        int l = tid + k * 256;            // float4 index
        float4 vv = ((const float4*)mbase)[l];
        int c = l >> 4, q = l & 15;
        *(float4*)&mlds[c * 68 + q * 4] = vv;
    }
    if (tid < 64) wlsh[tid] = w[o * 64 + tid];
    __syncthreads();

    {
        int uv = tid & 63, part = tid >> 6;
        float ss = 0.f;
#pragma unroll
        for (int j = 0; j < 16; ++j) {
            int c = part * 16 + j;
            float t = wlsh[c] * mlds[c * 68 + uv];
            ss += t * t;
        }
        red[part * 64 + uv] = ss;
    }
    __syncthreads();
    if (tid < 64) {
        float tot = red[tid] + red[64 + tid] + red[128 + tid] + red[192 + tid];
        rs[tid] = rsqrtf(fmaxf(tot, 1e-30f)) * (rows ? rows[o] : 1.f);
    }
    __syncthreads();

    {
        int uvw = tid >> 2, cp = tid & 3;
        float r = rs[uvw];
        size_t obase = ((size_t)(b * 64 + uvw) * NOUT + o) * 64;
#pragma unroll
        for (int g = 0; g < 2; ++g) {
            u16x8 pk;
#pragma unroll
            for (int e = 0; e < 8; ++e) {
                int c = cp * 16 + g * 8 + e;
                pk[e] = f2b(wlsh[c] * mlds[c * 68 + uvw] * r);
            }
            *(u16x8*)&out[obase + cp * 16 + g * 8] = pk;
        }
    }
}

// ---------------------------------------------------------------------------
// head_k: LN1 + conv1 (64->128). x fp32 -> t1 bf16. Weight frags direct from
// pw1. Grid (64 uv, 8 chunk, NB) -- uv fastest so all 8 chunk-blocks sharing
// one pw1 slice land on the same XCD. Block 256.
// ---------------------------------------------------------------------------
__global__ __launch_bounds__(256, 2) void head_k(
    const float* __restrict__ x, unsigned short* __restrict__ t1,
    const unsigned short* __restrict__ pw1, const float* __restrict__ b1,
    const float* __restrict__ n1w, const float* __restrict__ n1b, int bbase)
{
    const int tid   = threadIdx.x;
    const int uv    = blockIdx.x;
    const int chunk = blockIdx.y;
    const int z     = blockIdx.z;
    const int bfull = z + bbase;
    const int u = uv >> 3, v = uv & 7;
    const int h_base = u * 32 + chunk * 4;
    const int w_base = v * 32;

    __shared__ __align__(16) unsigned short stage[128 * 72];

    const int wave = tid >> 6;
    const int lane = tid & 63;
    const int q = lane >> 4;
    const int r = lane & 15;
    const int nfi[2] = {2 * wave, 2 * wave + 1};

    // B-frags + biases straight from global (L2-resident tables)
    const unsigned short* pwt = pw1 + ((size_t)(bfull * 64 + uv) * 128) * 64;
    bf16x8 bfr[2][2];
#pragma unroll
    for (int f = 0; f < 2; ++f)
#pragma unroll
        for (int ks = 0; ks < 2; ++ks)
            bfr[f][ks] = *(const bf16x8*)&pwt[(16 * nfi[f] + r) * 64 + ks * 32 + q * 8];
    float bsc[2] = {b1[16 * nfi[0] + r], b1[16 * nfi[1] + r]};

    // staging: thread = (pixel-quad qd, channel-octet cg); LN via shfl_xor
    const int cg = tid & 7;
    const int qd = tid >> 3;
    const int c0 = cg * 8;
    const int pixg = (h_base + (qd >> 3)) * 256 + w_base + (qd & 7) * 4;
    float v2[8][4];
#pragma unroll
    for (int k = 0; k < 8; ++k) {
        float4 t = *(const float4*)&x[((z * 64 + c0 + k) << 16) + pixg];
        v2[k][0] = t.x; v2[k][1] = t.y; v2[k][2] = t.z; v2[k][3] = t.w;
    }
    float lw[8], lb[8];
    *(float4*)&lw[0] = *(const float4*)&n1w[c0];
    *(float4*)&lw[4] = *(const float4*)&n1w[c0 + 4];
    *(float4*)&lb[0] = *(const float4*)&n1b[c0];
    *(float4*)&lb[4] = *(const float4*)&n1b[c0 + 4];
#pragma unroll
    for (int e = 0; e < 4; ++e) {
        float s1 = 0.f, s2 = 0.f;
#pragma unroll
        for (int k = 0; k < 8; ++k) { s1 += v2[k][e]; s2 += v2[k][e] * v2[k][e]; }
#pragma unroll
        for (int m = 1; m < 8; m <<= 1) { s1 += __shfl_xor(s1, m); s2 += __shfl_xor(s2, m); }
        float mu = s1 * (1.f / 64.f);
        float var = s2 * (1.f / 64.f) - mu * mu;
        float rstd = rsqrtf(fmaxf(var, 0.f) + 1e-6f);
        float o8[8];
#pragma unroll
        for (int k = 0; k < 8; ++k) o8[k] = (v2[k][e] - mu) * rstd * lw[k] + lb[k];
        uint4 pk;
        pk.x = pk2(o8[0], o8[1]); pk.y = pk2(o8[2], o8[3]);
        pk.z = pk2(o8[4], o8[5]); pk.w = pk2(o8[6], o8[7]);
        *(uint4*)&stage[(qd * 4 + e) * 72 + c0] = pk;
    }

    __syncthreads();

    f32x4 acc[8][2];
#pragma unroll
    for (int mi = 0; mi < 8; ++mi) { acc[mi][0] = (f32x4){0,0,0,0}; acc[mi][1] = (f32x4){0,0,0,0}; }
#pragma unroll
    for (int mi = 0; mi < 8; ++mi) {
        bf16x8 a0 = *(const bf16x8*)&stage[(16 * mi + r) * 72 + q * 8];
        bf16x8 a1 = *(const bf16x8*)&stage[(16 * mi + r) * 72 + 32 + q * 8];
#pragma unroll
        for (int f = 0; f < 2; ++f) {
            acc[mi][f] = __builtin_amdgcn_mfma_f32_16x16x32_bf16(a0, bfr[f][0], acc[mi][f], 0, 0, 0);
            acc[mi][f] = __builtin_amdgcn_mfma_f32_16x16x32_bf16(a1, bfr[f][1], acc[mi][f], 0, 0, 0);
        }
    }

#pragma unroll
    for (int mi = 0; mi < 8; ++mi) {
        int lp0 = 16 * mi + 4 * q;
        int pix = (h_base + (lp0 >> 5)) * 256 + w_base + (lp0 & 31);
#pragma unroll
        for (int f = 0; f < 2; ++f) {
            int o = 16 * nfi[f] + r;
            float bs = bsc[f];
            *(uint2*)&t1[((z * 128 + o) << 16) + pix] =
                make_uint2(pk2(acc[mi][f][0] + bs, acc[mi][f][1] + bs),
                           pk2(acc[mi][f][2] + bs, acc[mi][f][3] + bs));
        }
    }
}

// ---------------------------------------------------------------------------
// tail_k: sfin matvec (from s0) + conv3(+s,+beta,+x resid) -> y1 -> LN2 ->
// conv4 -> gate -> conv5(+gamma) -> out = y1 + z*gamma. One 128-px tile per
// block; y1/z never leave the block. Grid (64 uv, 8 chunk, NB), block 256.
// ---------------------------------------------------------------------------
__global__ __launch_bounds__(256, 2) void tail_k(
    const unsigned short* __restrict__ t3, const float* __restrict__ x,
    float* __restrict__ outp,
    const unsigned short* __restrict__ pw3, const float* __restrict__ b3,
    const float* __restrict__ beta,
    const unsigned short* __restrict__ pw4, const float* __restrict__ b4,
    const float* __restrict__ n2w, const float* __restrict__ n2b,
    const unsigned short* __restrict__ pw5, const float* __restrict__ b5,
    const float* __restrict__ gam,
    const float* __restrict__ scaw, const float* __restrict__ scab,
    const float* __restrict__ s0, int bbase)
{
    const int tid   = threadIdx.x;
    const int uv    = blockIdx.x;
    const int chunk = blockIdx.y;
    const int z     = blockIdx.z;
    const int bfull = z + bbase;
    const int u = uv >> 3, v = uv & 7;
    const int h_base = u * 32 + chunk * 4;
    const int w_base = v * 32;

    __shared__ __align__(16) unsigned short stage[128 * 72];
    __shared__ float sfin_l[64];

    const int wave = tid >> 6;
    const int lane = tid & 63;
    const int q = lane >> 4;
    const int r = lane & 15;
    const int oo = 16 * wave + r;          // this thread's out-channel (64-wide GEMMs)

    // ---- sfin = scaw @ (s0/65536) + scab, per block (scaw 16 KB, L2-hot) ----
    if (tid < 64) {
        const float* srow = scaw + tid * 64;
        const float* s0b  = s0 + bfull * 64;
        float acc = 0.f;
#pragma unroll
        for (int c4 = 0; c4 < 16; ++c4) {
            float4 wv = *(const float4*)&srow[c4 * 4];
            float4 s4 = *(const float4*)&s0b[c4 * 4];
            acc += wv.x * s4.x + wv.y * s4.y + wv.z * s4.z + wv.w * s4.w;
        }
        sfin_l[tid] = acc * (1.f / 65536.f) + scab[tid];
    }

    // ---- weight frags + per-lane scalars (global, L2) ----
    const unsigned short* p3 = pw3 + (size_t)(bfull * 64 + uv) * 64 * 64;
    const unsigned short* p4 = pw4 + (size_t)(bfull * 64 + uv) * 128 * 64;
    const unsigned short* p5 = pw5 + (size_t)(bfull * 64 + uv) * 64 * 64;
    bf16x8 w3f[2], w5f[2], w4f[2][2];
    const int nfi4[2] = {wave, wave + 4};  // gate pairs (o, o+64)
#pragma unroll
    for (int ks = 0; ks < 2; ++ks) {
        w3f[ks] = *(const bf16x8*)&p3[(oo) * 64 + ks * 32 + q * 8];
        w5f[ks] = *(const bf16x8*)&p5[(oo) * 64 + ks * 32 + q * 8];
#pragma unroll
        for (int f = 0; f < 2; ++f)
            w4f[f][ks] = *(const bf16x8*)&p4[(16 * nfi4[f] + r) * 64 + ks * 32 + q * 8];
    }
    const float sb3 = b3[oo] * beta[oo];
    const float ba4 = b4[oo], bg4 = b4[oo + 64];
    const float sb5 = b5[oo] * gam[oo];

    __syncthreads();   // sfin_l ready

    // ---- stage t3 (bf16) with sfin fold ----
    const int cg = tid & 7;
    const int qd = tid >> 3;
    const int c0 = cg * 8;
    const int pixg = (h_base + (qd >> 3)) * 256 + w_base + (qd & 7) * 4;
    {
        float sv[8];
        *(float4*)&sv[0] = *(const float4*)&sfin_l[c0];
        *(float4*)&sv[4] = *(const float4*)&sfin_l[c0 + 4];
        float v2[8][4];
#pragma unroll
        for (int k = 0; k < 8; ++k) {
            ushort4 t = *(const ushort4*)&t3[((z * 64 + c0 + k) << 16) + pixg];
            v2[k][0] = b2f(t.x) * sv[k]; v2[k][1] = b2f(t.y) * sv[k];
            v2[k][2] = b2f(t.z) * sv[k]; v2[k][3] = b2f(t.w) * sv[k];
        }
#pragma unroll
        for (int e = 0; e < 4; ++e) {
            uint4 pk;
            pk.x = pk2(v2[0][e], v2[1][e]); pk.y = pk2(v2[2][e], v2[3][e]);
            pk.z = pk2(v2[4][e], v2[5][e]); pk.w = pk2(v2[6][e], v2[7][e]);
            *(uint4*)&stage[(qd * 4 + e) * 72 + c0] = pk;
        }
    }
    __syncthreads();

    // ---- GEMM3: y = conv3(t3*s) (beta folded in pw3) ----
    f32x4 acc3[8];
#pragma unroll
    for (int mi = 0; mi < 8; ++mi) acc3[mi] = (f32x4){0, 0, 0, 0};
#pragma unroll
    for (int mi = 0; mi < 8; ++mi) {
        bf16x8 a0 = *(const bf16x8*)&stage[(16 * mi + r) * 72 + q * 8];
        bf16x8 a1 = *(const bf16x8*)&stage[(16 * mi + r) * 72 + 32 + q * 8];
        acc3[mi] = __builtin_amdgcn_mfma_f32_16x16x32_bf16(a0, w3f[0], acc3[mi], 0, 0, 0);
        acc3[mi] = __builtin_amdgcn_mfma_f32_16x16x32_bf16(a1, w3f[1], acc3[mi], 0, 0, 0);
    }
    __syncthreads();   // all stage reads done before overwrite

    // ---- y1 = x + conv3 result (fp32 in regs) ----
    float y1v[8][4];
#pragma unroll
    for (int mi = 0; mi < 8; ++mi) {
        int lp0 = 16 * mi + 4 * q;
        int pix = (h_base + (lp0 >> 5)) * 256 + w_base + (lp0 & 31);
        float4 xr = *(const float4*)&x[((z * 64 + oo) << 16) + pix];
        y1v[mi][0] = acc3[mi][0] + sb3 + xr.x;
        y1v[mi][1] = acc3[mi][1] + sb3 + xr.y;
        y1v[mi][2] = acc3[mi][2] + sb3 + xr.z;
        y1v[mi][3] = acc3[mi][3] + sb3 + xr.w;
    }
    // write y1 (bf16) to stage [px][ch]
#pragma unroll
    for (int mi = 0; mi < 8; ++mi)
#pragma unroll
        for (int e = 0; e < 4; ++e)
            stage[(16 * mi + 4 * q + e) * 72 + oo] = f2b(y1v[mi][e]);
    __syncthreads();

    // ---- LN2 in-place on stage ----
    {
        float lw[8], lb[8];
        *(float4*)&lw[0] = *(const float4*)&n2w[c0];
        *(float4*)&lw[4] = *(const float4*)&n2w[c0 + 4];
        *(float4*)&lb[0] = *(const float4*)&n2b[c0];
        *(float4*)&lb[4] = *(const float4*)&n2b[c0 + 4];
#pragma unroll
        for (int e = 0; e < 4; ++e) {
            int px = qd * 4 + e;
            uint4 raw = *(const uint4*)&stage[px * 72 + c0];
            unsigned short* rp = (unsigned short*)&raw;
            float vv[8];
            float s1 = 0.f, s2 = 0.f;
#pragma unroll
            for (int k = 0; k < 8; ++k) { vv[k] = b2f(rp[k]); s1 += vv[k]; s2 += vv[k] * vv[k]; }
#pragma unroll
            for (int m = 1; m < 8; m <<= 1) { s1 += __shfl_xor(s1, m); s2 += __shfl_xor(s2, m); }
            float mu = s1 * (1.f / 64.f);
            float var = s2 * (1.f / 64.f) - mu * mu;
            float rstd = rsqrtf(fmaxf(var, 0.f) + 1e-6f);
            float o8[8];
#pragma unroll
            for (int k = 0; k < 8; ++k) o8[k] = (vv[k] - mu) * rstd * lw[k] + lb[k];
            uint4 pk;
            pk.x = pk2(o8[0], o8[1]); pk.y = pk2(o8[2], o8[3]);
            pk.z = pk2(o8[4], o8[5]); pk.w = pk2(o8[6], o8[7]);
            *(uint4*)&stage[px * 72 + c0] = pk;
        }
    }
    __syncthreads();

    // ---- GEMM4 (64->128) + gate ----
    f32x4 acc4[8][2];
#pragma unroll
    for (int mi = 0; mi < 8; ++mi) { acc4[mi][0] = (f32x4){0,0,0,0}; acc4[mi][1] = (f32x4){0,0,0,0}; }
#pragma unroll
    for (int mi = 0; mi < 8; ++mi) {
        bf16x8 a0 = *(const bf16x8*)&stage[(16 * mi + r) * 72 + q * 8];
        bf16x8 a1 = *(const bf16x8*)&stage[(16 * mi + r) * 72 + 32 + q * 8];
#pragma unroll
        for (int f = 0; f < 2; ++f) {
            acc4[mi][f] = __builtin_amdgcn_mfma_f32_16x16x32_bf16(a0, w4f[f][0], acc4[mi][f], 0, 0, 0);
            acc4[mi][f] = __builtin_amdgcn_mfma_f32_16x16x32_bf16(a1, w4f[f][1], acc4[mi][f], 0, 0, 0);
        }
    }
    __syncthreads();   // stage reads done
#pragma unroll
    for (int mi = 0; mi < 8; ++mi)
#pragma unroll
        for (int e = 0; e < 4; ++e) {
            float zv = (acc4[mi][0][e] + ba4) * (acc4[mi][1][e] + bg4);
            stage[(16 * mi + 4 * q + e) * 72 + oo] = f2b(zv);
        }
    __syncthreads();

    // ---- GEMM5 (64->64, gamma folded) + final residual ----
    f32x4 acc5[8];
#pragma unroll
    for (int mi = 0; mi < 8; ++mi) acc5[mi] = (f32x4){0, 0, 0, 0};
#pragma unroll
    for (int mi = 0; mi < 8; ++mi) {
        bf16x8 a0 = *(const bf16x8*)&stage[(16 * mi + r) * 72 + q * 8];
        bf16x8 a1 = *(const bf16x8*)&stage[(16 * mi + r) * 72 + 32 + q * 8];
        acc5[mi] = __builtin_amdgcn_mfma_f32_16x16x32_bf16(a0, w5f[0], acc5[mi], 0, 0, 0);
        acc5[mi] = __builtin_amdgcn_mfma_f32_16x16x32_bf16(a1, w5f[1], acc5[mi], 0, 0, 0);
    }
#pragma unroll
    for (int mi = 0; mi < 8; ++mi) {
        int lp0 = 16 * mi + 4 * q;
        int pix = (h_base + (lp0 >> 5)) * 256 + w_base + (lp0 & 31);
        *(float4*)&outp[((z * 64 + oo) << 16) + pix] =
            make_float4(y1v[mi][0] + acc5[mi][0] + sb5,
                        y1v[mi][1] + acc5[mi][1] + sb5,
                        y1v[mi][2] + acc5[mi][2] + sb5,
                        y1v[mi][3] + acc5[mi][3] + sb5);
    }
}

// ---------------------------------------------------------------------------
// dw_k: depthwise 3x3 modulated + gate + SCA partials. 8 px/thread, direct
// global vector loads, halo via shuffles (image-border zeros).
// Grid: (64 oc, 32 row-bands of 8, NB) -- oc fastest so adjacent bands of the
// same channel (sharing halo rows) land on the same XCD. Block 256.
// ---------------------------------------------------------------------------
__global__ __launch_bounds__(256, 4) void dw_k(
    const unsigned short* __restrict__ t1,   // (NB,128,H,W) bf16
    unsigned short* __restrict__ t3,         // (NB,64,H,W) bf16
    const float* __restrict__ w2,            // (128,3,3)
    const float* __restrict__ b2,            // (128)
    const float* __restrict__ mod2,          // (2,128,8,8)
    float* __restrict__ s0,                  // (2,64)
    int bbase)
{
    const int tid  = threadIdx.x;
    const int oc   = blockIdx.x;
    const int band = blockIdx.y;
    const int z    = blockIdx.z;
    const int bfull = z + bbase;
    const int u = band >> 2;

    __shared__ float wl[2][8][9];
    __shared__ float wred[4];

    if (tid < 16) {
        int halfc = tid >> 3, vv = tid & 7;
        const float* wrow = w2 + (oc + halfc * 64) * 9;
        float wloc[9], ssum = 0.f;
#pragma unroll
        for (int k = 0; k < 9; ++k) { wloc[k] = wrow[k]; ssum += wloc[k] * wloc[k]; }
        float m = mod2[(bfull * 128 + oc + halfc * 64) * 64 + u * 8 + vv];
        float rn = m * rsqrtf(fmaxf(m * m * ssum, 1e-30f));
#pragma unroll
        for (int k = 0; k < 9; ++k) wl[halfc][vv][k] = wloc[k] * rn;
    }
    __syncthreads();

    const int strip = tid & 31;
    const int row   = band * 8 + (tid >> 5);
    const int v     = strip >> 2;

    float wa[9], wg[9];
#pragma unroll
    for (int k = 0; k < 9; ++k) { wa[k] = wl[0][v][k]; wg[k] = wl[1][v][k]; }
    const float ba = b2[oc], bg = b2[oc + 64];

    const unsigned short* pa = t1 + (((size_t)z * 128 + oc) << 16);
    const unsigned short* pg = pa + ((size_t)64 << 16);

    float fa[3][8], fg[3][8], la[3], ra[3], lg[3], rg[3];
#pragma unroll
    for (int dr = 0; dr < 3; ++dr) {
        int rr = row - 1 + dr;
        if (rr >= 0 && rr < 256) {
            u16x8 va = *(const u16x8*)&pa[rr * 256 + strip * 8];
            u16x8 vg = *(const u16x8*)&pg[rr * 256 + strip * 8];
#pragma unroll
            for (int e = 0; e < 8; ++e) { fa[dr][e] = b2f(va[e]); fg[dr][e] = b2f(vg[e]); }
        } else {
#pragma unroll
            for (int e = 0; e < 8; ++e) { fa[dr][e] = 0.f; fg[dr][e] = 0.f; }
        }
        float t;
        t = __shfl_up(fa[dr][7], 1);   la[dr] = (strip == 0)  ? 0.f : t;
        t = __shfl_up(fg[dr][7], 1);   lg[dr] = (strip == 0)  ? 0.f : t;
        t = __shfl_down(fa[dr][0], 1); ra[dr] = (strip == 31) ? 0.f : t;
        t = __shfl_down(fg[dr][0], 1); rg[dr] = (strip == 31) ? 0.f : t;
    }

    float psum = 0.f;
    u16x8 pk;
#pragma unroll
    for (int j = 0; j < 8; ++j) {
        float a = 0.f, g = 0.f;
#pragma unroll
        for (int dr = 0; dr < 3; ++dr) {
            float m1a = (j == 0) ? la[dr] : fa[dr][j - 1];
            float p1a = (j == 7) ? ra[dr] : fa[dr][j + 1];
            float m1g = (j == 0) ? lg[dr] : fg[dr][j - 1];
            float p1g = (j == 7) ? rg[dr] : fg[dr][j + 1];
            a += wa[dr * 3] * m1a + wa[dr * 3 + 1] * fa[dr][j] + wa[dr * 3 + 2] * p1a;
            g += wg[dr * 3] * m1g + wg[dr * 3 + 1] * fg[dr][j] + wg[dr * 3 + 2] * p1g;
        }
        float val = (a + ba) * (g + bg);
        psum += val;
        pk[j] = f2b(val);
    }
    *(u16x8*)&t3[(((size_t)z * 64 + oc) << 16) + row * 256 + strip * 8] = pk;

    for (int off = 32; off > 0; off >>= 1) psum += __shfl_down(psum, off, 64);
    if ((tid & 63) == 0) wred[tid >> 6] = psum;
    __syncthreads();
    if (tid == 0)
        atomicAdd(&s0[bfull * 64 + oc], wred[0] + wred[1] + wred[2] + wred[3]);
}

// ---------------------------------------------------------------------------
extern "C" void kernel_launch(void* const* d_in, const int* in_sizes, int n_in,
                              void* d_out, int out_size, void* d_ws, size_t ws_size,
                              hipStream_t stream) {
    (void)in_sizes; (void)n_in; (void)out_size;
    const float* x    = (const float*)d_in[0];
    const float* w1   = (const float*)d_in[1];
    const float* b1   = (const float*)d_in[2];
    const float* w2   = (const float*)d_in[3];
    const float* b2   = (const float*)d_in[4];
    const float* w3   = (const float*)d_in[5];
    const float* b3   = (const float*)d_in[6];
    const float* scaw = (const float*)d_in[7];
    const float* scab = (const float*)d_in[8];
    const float* w4   = (const float*)d_in[9];
    const float* b4   = (const float*)d_in[10];
    const float* w5   = (const float*)d_in[11];
    const float* b5   = (const float*)d_in[12];
    const float* n1w  = (const float*)d_in[13];
    const float* n1b  = (const float*)d_in[14];
    const float* n2w  = (const float*)d_in[15];
    const float* n2b  = (const float*)d_in[16];
    const float* beta = (const float*)d_in[17];
    const float* gam  = (const float*)d_in[18];
    const float* mod1 = (const float*)d_in[19];
    const float* mod2 = (const float*)d_in[20];
    const float* mod3 = (const float*)d_in[21];
    const float* mod4 = (const float*)d_in[22];
    const float* mod5 = (const float*)d_in[23];

    char* ws = (char*)d_ws;
    float* outf = (float*)d_out;

    const size_t IMGel = (size_t)64 * 65536;
    const size_t T1B   = (size_t)128 * 65536 * 2;   // 16.78 MB per batch
    const size_t T3B   = (size_t)64 * 65536 * 2;    // 8.39 MB per batch
    const size_t PW1B = 2097152, PW3B = 1048576, PW4B = 2097152, PW5B = 1048576;
    const size_t TBLB = PW1B + PW3B + PW4B + PW5B;  // 6.29 MB

    const size_t needA = 2 * (T1B + T3B) + 4096 + TBLB;   // ~56.6 MB
    const bool planA = ws_size >= needA;                  // ws measured ~268 MB
    const size_t NBT = planA ? 2 : 1;

    unsigned short* t1 = (unsigned short*)ws;
    unsigned short* t3 = (unsigned short*)(ws + NBT * T1B);
    char* statb = ws + NBT * (T1B + T3B);
    float* s0   = (float*)statb;
    unsigned short* pw1 = (unsigned short*)(statb + 4096);
    unsigned short* pw3 = (unsigned short*)(statb + 4096 + PW1B);
    unsigned short* pw4 = (unsigned short*)(statb + 4096 + PW1B + PW3B);
    unsigned short* pw5 = (unsigned short*)(statb + 4096 + PW1B + PW3B + PW4B);

    dim3 blk(256);

    prep_k<<<768, blk, 0, stream>>>(w1, mod1, w3, mod3, beta, w4, mod4,
                                    w5, mod5, gam, pw1, pw3, pw4, pw5, s0);

    if (planA) {
        dim3 gconv(64, 8, 2), gdw(64, 32, 2);
        head_k<<<gconv, blk, 0, stream>>>(x, t1, pw1, b1, n1w, n1b, 0);
        dw_k<<<gdw, blk, 0, stream>>>(t1, t3, w2, b2, mod2, s0, 0);
        tail_k<<<gconv, blk, 0, stream>>>(t3, x, outf, pw3, b3, beta,
                                          pw4, b4, n2w, n2b, pw5, b5, gam,
                                          scaw, scab, s0, 0);
    } else {
        for (int bb = 0; bb < 2; ++bb) {
            const float* x_b   = x    + (size_t)bb * IMGel;
            float*       out_b = outf + (size_t)bb * IMGel;
            dim3 gconv(64, 8, 1), gdw(64, 32, 1);
            head_k<<<gconv, blk, 0, stream>>>(x_b, t1, pw1, b1, n1w, n1b, bb);
            dw_k<<<gdw, blk, 0, stream>>>(t1, t3, w2, b2, mod2, s0, bb);
            tail_k<<<gconv, blk, 0, stream>>>(t3, x_b, out_b, pw3, b3, beta,
                                              pw4, b4, n2w, n2b, pw5, b5, gam,
                                              scaw, scab, s0, bb);
        }
    }
}

// Round 3
// 200.221 us; speedup vs baseline: 1.0251x; 1.0101x over previous
//
#include <hip/hip_runtime.h>
#include <hip/hip_bf16.h>

// ---------------------------------------------------------------------------
// NAFNet-like block, MI355X (gfx950). B=2,C=64,H=W=256,DW=128,FFN=128,GRID=8.
// fp32 true inputs + fp32 output; bf16 intermediates; MFMA 16x16x32 bf16.
// R8b: occupancy push (compile fix: nontemporal store via ext_vector f32x4).
//     head (256,4), tail (256,3); tail prefetches residual x at kernel top;
//     out stores nontemporal; dw_k computes 3x3 weights per-thread.
// ---------------------------------------------------------------------------

typedef __bf16 bf16x8 __attribute__((ext_vector_type(8)));
typedef float f32x4 __attribute__((ext_vector_type(4)));
typedef unsigned short u16x8 __attribute__((ext_vector_type(8)));

__device__ __forceinline__ float b2f(unsigned short u) {
    union { unsigned int i; float f; } x; x.i = ((unsigned int)u) << 16; return x.f;
}
__device__ __forceinline__ unsigned short f2b(float f) {
    union { float f; unsigned int i; } x; x.f = f;
    unsigned int i = x.i;
    return (unsigned short)((i + 0x7FFFu + ((i >> 16) & 1u)) >> 16);  // RNE
}
__device__ __forceinline__ unsigned int pk2(float a, float b) {
    __hip_bfloat162 h = __float22bfloat162_rn(float2{a, b});  // v_cvt_pk_bf16_f32
    union { __hip_bfloat162 h; unsigned int u; } cv; cv.h = h; return cv.u;
}

// ---------------------------------------------------------------------------
// prep_k: demodulated bf16 weight tables [b][uv][o][c] for conv1/3/4/5.
// Grid 768 = 256(conv1) + 128(conv3,beta) + 256(conv4) + 128(conv5,gamma).
// Also zeroes s0 (block 0) so no separate memset dispatch is needed.
// ---------------------------------------------------------------------------
__global__ __launch_bounds__(256) void prep_k(
    const float* __restrict__ w1, const float* __restrict__ mod1,
    const float* __restrict__ w3, const float* __restrict__ mod3,
    const float* __restrict__ beta,
    const float* __restrict__ w4, const float* __restrict__ mod4,
    const float* __restrict__ w5, const float* __restrict__ mod5,
    const float* __restrict__ gam,
    unsigned short* __restrict__ pw1, unsigned short* __restrict__ pw3,
    unsigned short* __restrict__ pw4, unsigned short* __restrict__ pw5,
    float* __restrict__ s0)
{
    const int tid = threadIdx.x;
    int blk = blockIdx.x;
    if (blk == 0 && tid < 128) s0[tid] = 0.f;   // consumed only by dw_k/tail_k later
    const float* w; const float* mod; const float* rows = nullptr;
    unsigned short* out; int NOUT; int rem;
    if (blk < 256)      { w = w1; mod = mod1; out = pw1; NOUT = 128; rem = blk; }
    else if (blk < 384) { w = w3; mod = mod3; out = pw3; NOUT = 64;  rem = blk - 256; rows = beta; }
    else if (blk < 640) { w = w4; mod = mod4; out = pw4; NOUT = 128; rem = blk - 384; }
    else                { w = w5; mod = mod5; out = pw5; NOUT = 64;  rem = blk - 640; rows = gam; }
    const int b = rem / NOUT, o = rem % NOUT;

    __shared__ float mlds[64 * 68];   // [c][uv], pad 68
    __shared__ float wlsh[64];
    __shared__ float red[4 * 64];
    __shared__ float rs[64];

    const float* mbase = mod + ((size_t)(b * NOUT + o) * 64) * 64;  // [c][uv]
#pragma unroll
    for (int k = 0; k < 4; ++k) {
        int l = tid + k * 256;            // float4 index
        float4 vv = ((const float4*)mbase)[l];
        int c = l >> 4, q = l & 15;
        *(float4*)&mlds[c * 68 + q * 4] = vv;
    }
    if (tid < 64) wlsh[tid] = w[o * 64 + tid];
    __syncthreads();

    {
        int uv = tid & 63, part = tid >> 6;
        float ss = 0.f;
#pragma unroll
        for (int j = 0; j < 16; ++j) {
            int c = part * 16 + j;
            float t = wlsh[c] * mlds[c * 68 + uv];
            ss += t * t;
        }
        red[part * 64 + uv] = ss;
    }
    __syncthreads();
    if (tid < 64) {
        float tot = red[tid] + red[64 + tid] + red[128 + tid] + red[192 + tid];
        rs[tid] = rsqrtf(fmaxf(tot, 1e-30f)) * (rows ? rows[o] : 1.f);
    }
    __syncthreads();

    {
        int uvw = tid >> 2, cp = tid & 3;
        float r = rs[uvw];
        size_t obase = ((size_t)(b * 64 + uvw) * NOUT + o) * 64;
#pragma unroll
        for (int g = 0; g < 2; ++g) {
            u16x8 pk;
#pragma unroll
            for (int e = 0; e < 8; ++e) {
                int c = cp * 16 + g * 8 + e;
                pk[e] = f2b(wlsh[c] * mlds[c * 68 + uvw] * r);
            }
            *(u16x8*)&out[obase + cp * 16 + g * 8] = pk;
        }
    }
}

// ---------------------------------------------------------------------------
// head_k: LN1 + conv1 (64->128). x fp32 -> t1 bf16. Weight frags direct from
// pw1. Grid (64 uv, 8 chunk, NB), block 256. (256,4): peak live regs ~95.
// ---------------------------------------------------------------------------
__global__ __launch_bounds__(256, 4) void head_k(
    const float* __restrict__ x, unsigned short* __restrict__ t1,
    const unsigned short* __restrict__ pw1, const float* __restrict__ b1,
    const float* __restrict__ n1w, const float* __restrict__ n1b, int bbase)
{
    const int tid   = threadIdx.x;
    const int uv    = blockIdx.x;
    const int chunk = blockIdx.y;
    const int z     = blockIdx.z;
    const int bfull = z + bbase;
    const int u = uv >> 3, v = uv & 7;
    const int h_base = u * 32 + chunk * 4;
    const int w_base = v * 32;

    __shared__ __align__(16) unsigned short stage[128 * 72];

    const int wave = tid >> 6;
    const int lane = tid & 63;
    const int q = lane >> 4;
    const int r = lane & 15;
    const int nfi[2] = {2 * wave, 2 * wave + 1};

    // B-frags + biases straight from global (L2-resident tables)
    const unsigned short* pwt = pw1 + ((size_t)(bfull * 64 + uv) * 128) * 64;
    bf16x8 bfr[2][2];
#pragma unroll
    for (int f = 0; f < 2; ++f)
#pragma unroll
        for (int ks = 0; ks < 2; ++ks)
            bfr[f][ks] = *(const bf16x8*)&pwt[(16 * nfi[f] + r) * 64 + ks * 32 + q * 8];
    float bsc[2] = {b1[16 * nfi[0] + r], b1[16 * nfi[1] + r]};

    // staging: thread = (pixel-quad qd, channel-octet cg); LN via shfl_xor
    const int cg = tid & 7;
    const int qd = tid >> 3;
    const int c0 = cg * 8;
    const int pixg = (h_base + (qd >> 3)) * 256 + w_base + (qd & 7) * 4;
    float v2[8][4];
#pragma unroll
    for (int k = 0; k < 8; ++k) {
        float4 t = *(const float4*)&x[((z * 64 + c0 + k) << 16) + pixg];
        v2[k][0] = t.x; v2[k][1] = t.y; v2[k][2] = t.z; v2[k][3] = t.w;
    }
    float lw[8], lb[8];
    *(float4*)&lw[0] = *(const float4*)&n1w[c0];
    *(float4*)&lw[4] = *(const float4*)&n1w[c0 + 4];
    *(float4*)&lb[0] = *(const float4*)&n1b[c0];
    *(float4*)&lb[4] = *(const float4*)&n1b[c0 + 4];
#pragma unroll
    for (int e = 0; e < 4; ++e) {
        float s1 = 0.f, s2 = 0.f;
#pragma unroll
        for (int k = 0; k < 8; ++k) { s1 += v2[k][e]; s2 += v2[k][e] * v2[k][e]; }
#pragma unroll
        for (int m = 1; m < 8; m <<= 1) { s1 += __shfl_xor(s1, m); s2 += __shfl_xor(s2, m); }
        float mu = s1 * (1.f / 64.f);
        float var = s2 * (1.f / 64.f) - mu * mu;
        float rstd = rsqrtf(fmaxf(var, 0.f) + 1e-6f);
        float o8[8];
#pragma unroll
        for (int k = 0; k < 8; ++k) o8[k] = (v2[k][e] - mu) * rstd * lw[k] + lb[k];
        uint4 pk;
        pk.x = pk2(o8[0], o8[1]); pk.y = pk2(o8[2], o8[3]);
        pk.z = pk2(o8[4], o8[5]); pk.w = pk2(o8[6], o8[7]);
        *(uint4*)&stage[(qd * 4 + e) * 72 + c0] = pk;
    }

    __syncthreads();

    f32x4 acc[8][2];
#pragma unroll
    for (int mi = 0; mi < 8; ++mi) { acc[mi][0] = (f32x4){0,0,0,0}; acc[mi][1] = (f32x4){0,0,0,0}; }
#pragma unroll
    for (int mi = 0; mi < 8; ++mi) {
        bf16x8 a0 = *(const bf16x8*)&stage[(16 * mi + r) * 72 + q * 8];
        bf16x8 a1 = *(const bf16x8*)&stage[(16 * mi + r) * 72 + 32 + q * 8];
#pragma unroll
        for (int f = 0; f < 2; ++f) {
            acc[mi][f] = __builtin_amdgcn_mfma_f32_16x16x32_bf16(a0, bfr[f][0], acc[mi][f], 0, 0, 0);
            acc[mi][f] = __builtin_amdgcn_mfma_f32_16x16x32_bf16(a1, bfr[f][1], acc[mi][f], 0, 0, 0);
        }
    }

#pragma unroll
    for (int mi = 0; mi < 8; ++mi) {
        int lp0 = 16 * mi + 4 * q;
        int pix = (h_base + (lp0 >> 5)) * 256 + w_base + (lp0 & 31);
#pragma unroll
        for (int f = 0; f < 2; ++f) {
            int o = 16 * nfi[f] + r;
            float bs = bsc[f];
            *(uint2*)&t1[((z * 128 + o) << 16) + pix] =
                make_uint2(pk2(acc[mi][f][0] + bs, acc[mi][f][1] + bs),
                           pk2(acc[mi][f][2] + bs, acc[mi][f][3] + bs));
        }
    }
}

// ---------------------------------------------------------------------------
// tail_k: sfin matvec (from s0) + conv3(+s,+beta,+x resid) -> y1 -> LN2 ->
// conv4 -> gate -> conv5(+gamma) -> out = y1 + z*gamma. One 128-px tile per
// block. Residual x prefetched at kernel top. Grid (64 uv, 8 chunk, NB).
// ---------------------------------------------------------------------------
__global__ __launch_bounds__(256, 3) void tail_k(
    const unsigned short* __restrict__ t3, const float* __restrict__ x,
    float* __restrict__ outp,
    const unsigned short* __restrict__ pw3, const float* __restrict__ b3,
    const float* __restrict__ beta,
    const unsigned short* __restrict__ pw4, const float* __restrict__ b4,
    const float* __restrict__ n2w, const float* __restrict__ n2b,
    const unsigned short* __restrict__ pw5, const float* __restrict__ b5,
    const float* __restrict__ gam,
    const float* __restrict__ scaw, const float* __restrict__ scab,
    const float* __restrict__ s0, int bbase)
{
    const int tid   = threadIdx.x;
    const int uv    = blockIdx.x;
    const int chunk = blockIdx.y;
    const int z     = blockIdx.z;
    const int bfull = z + bbase;
    const int u = uv >> 3, v = uv & 7;
    const int h_base = u * 32 + chunk * 4;
    const int w_base = v * 32;

    __shared__ __align__(16) unsigned short stage[128 * 72];
    __shared__ float sfin_l[64];

    const int wave = tid >> 6;
    const int lane = tid & 63;
    const int q = lane >> 4;
    const int r = lane & 15;
    const int oo = 16 * wave + r;          // this thread's out-channel (64-wide GEMMs)

    // ---- prefetch residual x early: no deps, latency hides under everything ----
    float4 xr8[8];
#pragma unroll
    for (int mi = 0; mi < 8; ++mi) {
        int lp0 = 16 * mi + 4 * q;
        int pix = (h_base + (lp0 >> 5)) * 256 + w_base + (lp0 & 31);
        xr8[mi] = *(const float4*)&x[((z * 64 + oo) << 16) + pix];
    }

    // ---- sfin = scaw @ (s0/65536) + scab, per block (scaw 16 KB, L2-hot) ----
    if (tid < 64) {
        const float* srow = scaw + tid * 64;
        const float* s0b  = s0 + bfull * 64;
        float acc = 0.f;
#pragma unroll
        for (int c4 = 0; c4 < 16; ++c4) {
            float4 wv = *(const float4*)&srow[c4 * 4];
            float4 s4 = *(const float4*)&s0b[c4 * 4];
            acc += wv.x * s4.x + wv.y * s4.y + wv.z * s4.z + wv.w * s4.w;
        }
        sfin_l[tid] = acc * (1.f / 65536.f) + scab[tid];
    }

    // ---- weight frags + per-lane scalars (global, L2) ----
    const unsigned short* p3 = pw3 + (size_t)(bfull * 64 + uv) * 64 * 64;
    const unsigned short* p4 = pw4 + (size_t)(bfull * 64 + uv) * 128 * 64;
    const unsigned short* p5 = pw5 + (size_t)(bfull * 64 + uv) * 64 * 64;
    bf16x8 w3f[2], w5f[2], w4f[2][2];
    const int nfi4[2] = {wave, wave + 4};  // gate pairs (o, o+64)
#pragma unroll
    for (int ks = 0; ks < 2; ++ks) {
        w3f[ks] = *(const bf16x8*)&p3[(oo) * 64 + ks * 32 + q * 8];
        w5f[ks] = *(const bf16x8*)&p5[(oo) * 64 + ks * 32 + q * 8];
#pragma unroll
        for (int f = 0; f < 2; ++f)
            w4f[f][ks] = *(const bf16x8*)&p4[(16 * nfi4[f] + r) * 64 + ks * 32 + q * 8];
    }
    const float sb3 = b3[oo] * beta[oo];
    const float ba4 = b4[oo], bg4 = b4[oo + 64];
    const float sb5 = b5[oo] * gam[oo];

    __syncthreads();   // sfin_l ready

    // ---- stage t3 (bf16) with sfin fold ----
    const int cg = tid & 7;
    const int qd = tid >> 3;
    const int c0 = cg * 8;
    const int pixg = (h_base + (qd >> 3)) * 256 + w_base + (qd & 7) * 4;
    {
        float sv[8];
        *(float4*)&sv[0] = *(const float4*)&sfin_l[c0];
        *(float4*)&sv[4] = *(const float4*)&sfin_l[c0 + 4];
        float v2[8][4];
#pragma unroll
        for (int k = 0; k < 8; ++k) {
            ushort4 t = *(const ushort4*)&t3[((z * 64 + c0 + k) << 16) + pixg];
            v2[k][0] = b2f(t.x) * sv[k]; v2[k][1] = b2f(t.y) * sv[k];
            v2[k][2] = b2f(t.z) * sv[k]; v2[k][3] = b2f(t.w) * sv[k];
        }
#pragma unroll
        for (int e = 0; e < 4; ++e) {
            uint4 pk;
            pk.x = pk2(v2[0][e], v2[1][e]); pk.y = pk2(v2[2][e], v2[3][e]);
            pk.z = pk2(v2[4][e], v2[5][e]); pk.w = pk2(v2[6][e], v2[7][e]);
            *(uint4*)&stage[(qd * 4 + e) * 72 + c0] = pk;
        }
    }
    __syncthreads();

    // ---- GEMM3: y = conv3(t3*s) (beta folded in pw3) ----
    f32x4 acc3[8];
#pragma unroll
    for (int mi = 0; mi < 8; ++mi) acc3[mi] = (f32x4){0, 0, 0, 0};
#pragma unroll
    for (int mi = 0; mi < 8; ++mi) {
        bf16x8 a0 = *(const bf16x8*)&stage[(16 * mi + r) * 72 + q * 8];
        bf16x8 a1 = *(const bf16x8*)&stage[(16 * mi + r) * 72 + 32 + q * 8];
        acc3[mi] = __builtin_amdgcn_mfma_f32_16x16x32_bf16(a0, w3f[0], acc3[mi], 0, 0, 0);
        acc3[mi] = __builtin_amdgcn_mfma_f32_16x16x32_bf16(a1, w3f[1], acc3[mi], 0, 0, 0);
    }
    __syncthreads();   // all stage reads done before overwrite

    // ---- y1 = x + conv3 result (fp32 in regs) ----
    float y1v[8][4];
#pragma unroll
    for (int mi = 0; mi < 8; ++mi) {
        y1v[mi][0] = acc3[mi][0] + sb3 + xr8[mi].x;
        y1v[mi][1] = acc3[mi][1] + sb3 + xr8[mi].y;
        y1v[mi][2] = acc3[mi][2] + sb3 + xr8[mi].z;
        y1v[mi][3] = acc3[mi][3] + sb3 + xr8[mi].w;
    }
    // write y1 (bf16) to stage [px][ch]
#pragma unroll
    for (int mi = 0; mi < 8; ++mi)
#pragma unroll
        for (int e = 0; e < 4; ++e)
            stage[(16 * mi + 4 * q + e) * 72 + oo] = f2b(y1v[mi][e]);
    __syncthreads();

    // ---- LN2 in-place on stage ----
    {
        float lw[8], lb[8];
        *(float4*)&lw[0] = *(const float4*)&n2w[c0];
        *(float4*)&lw[4] = *(const float4*)&n2w[c0 + 4];
        *(float4*)&lb[0] = *(const float4*)&n2b[c0];
        *(float4*)&lb[4] = *(const float4*)&n2b[c0 + 4];
#pragma unroll
        for (int e = 0; e < 4; ++e) {
            int px = qd * 4 + e;
            uint4 raw = *(const uint4*)&stage[px * 72 + c0];
            unsigned short* rp = (unsigned short*)&raw;
            float vv[8];
            float s1 = 0.f, s2 = 0.f;
#pragma unroll
            for (int k = 0; k < 8; ++k) { vv[k] = b2f(rp[k]); s1 += vv[k]; s2 += vv[k] * vv[k]; }
#pragma unroll
            for (int m = 1; m < 8; m <<= 1) { s1 += __shfl_xor(s1, m); s2 += __shfl_xor(s2, m); }
            float mu = s1 * (1.f / 64.f);
            float var = s2 * (1.f / 64.f) - mu * mu;
            float rstd = rsqrtf(fmaxf(var, 0.f) + 1e-6f);
            float o8[8];
#pragma unroll
            for (int k = 0; k < 8; ++k) o8[k] = (vv[k] - mu) * rstd * lw[k] + lb[k];
            uint4 pk;
            pk.x = pk2(o8[0], o8[1]); pk.y = pk2(o8[2], o8[3]);
            pk.z = pk2(o8[4], o8[5]); pk.w = pk2(o8[6], o8[7]);
            *(uint4*)&stage[px * 72 + c0] = pk;
        }
    }
    __syncthreads();

    // ---- GEMM4 (64->128) + gate ----
    f32x4 acc4[8][2];
#pragma unroll
    for (int mi = 0; mi < 8; ++mi) { acc4[mi][0] = (f32x4){0,0,0,0}; acc4[mi][1] = (f32x4){0,0,0,0}; }
#pragma unroll
    for (int mi = 0; mi < 8; ++mi) {
        bf16x8 a0 = *(const bf16x8*)&stage[(16 * mi + r) * 72 + q * 8];
        bf16x8 a1 = *(const bf16x8*)&stage[(16 * mi + r) * 72 + 32 + q * 8];
#pragma unroll
        for (int f = 0; f < 2; ++f) {
            acc4[mi][f] = __builtin_amdgcn_mfma_f32_16x16x32_bf16(a0, w4f[f][0], acc4[mi][f], 0, 0, 0);
            acc4[mi][f] = __builtin_amdgcn_mfma_f32_16x16x32_bf16(a1, w4f[f][1], acc4[mi][f], 0, 0, 0);
        }
    }
    __syncthreads();   // stage reads done
#pragma unroll
    for (int mi = 0; mi < 8; ++mi)
#pragma unroll
        for (int e = 0; e < 4; ++e) {
            float zv = (acc4[mi][0][e] + ba4) * (acc4[mi][1][e] + bg4);
            stage[(16 * mi + 4 * q + e) * 72 + oo] = f2b(zv);
        }
    __syncthreads();

    // ---- GEMM5 (64->64, gamma folded) + final residual ----
    f32x4 acc5[8];
#pragma unroll
    for (int mi = 0; mi < 8; ++mi) acc5[mi] = (f32x4){0, 0, 0, 0};
#pragma unroll
    for (int mi = 0; mi < 8; ++mi) {
        bf16x8 a0 = *(const bf16x8*)&stage[(16 * mi + r) * 72 + q * 8];
        bf16x8 a1 = *(const bf16x8*)&stage[(16 * mi + r) * 72 + 32 + q * 8];
        acc5[mi] = __builtin_amdgcn_mfma_f32_16x16x32_bf16(a0, w5f[0], acc5[mi], 0, 0, 0);
        acc5[mi] = __builtin_amdgcn_mfma_f32_16x16x32_bf16(a1, w5f[1], acc5[mi], 0, 0, 0);
    }
#pragma unroll
    for (int mi = 0; mi < 8; ++mi) {
        int lp0 = 16 * mi + 4 * q;
        int pix = (h_base + (lp0 >> 5)) * 256 + w_base + (lp0 & 31);
        f32x4 ov = {y1v[mi][0] + acc5[mi][0] + sb5,
                    y1v[mi][1] + acc5[mi][1] + sb5,
                    y1v[mi][2] + acc5[mi][2] + sb5,
                    y1v[mi][3] + acc5[mi][3] + sb5};
        __builtin_nontemporal_store(ov, (f32x4*)&outp[((z * 64 + oo) << 16) + pix]);
    }
}

// ---------------------------------------------------------------------------
// dw_k: depthwise 3x3 modulated + gate + SCA partials. 8 px/thread, direct
// global vector loads, halo via shuffles (image-border zeros). Weights
// computed per-thread (scalar w2 loads) -- no LDS staging, no first barrier.
// Grid: (64 oc, 32 row-bands of 8, NB). Block 256.
// ---------------------------------------------------------------------------
__global__ __launch_bounds__(256, 4) void dw_k(
    const unsigned short* __restrict__ t1,   // (NB,128,H,W) bf16
    unsigned short* __restrict__ t3,         // (NB,64,H,W) bf16
    const float* __restrict__ w2,            // (128,3,3)
    const float* __restrict__ b2,            // (128)
    const float* __restrict__ mod2,          // (2,128,8,8)
    float* __restrict__ s0,                  // (2,64)
    int bbase)
{
    const int tid  = threadIdx.x;
    const int oc   = blockIdx.x;
    const int band = blockIdx.y;
    const int z    = blockIdx.z;
    const int bfull = z + bbase;
    const int u = band >> 2;

    __shared__ float wred[4];

    const int strip = tid & 31;
    const int row   = band * 8 + (tid >> 5);
    const int v     = strip >> 2;

    // per-thread demodulated 3x3 weights: w2 rows are wave-uniform (s_load),
    // mod2 per-lane (v). Replaces 16-thread LDS staging + barrier.
    float wa[9], wg[9];
    {
        const float* wra = w2 + oc * 9;
        const float* wrg = w2 + (oc + 64) * 9;
        float ssa = 0.f, ssg = 0.f;
#pragma unroll
        for (int k = 0; k < 9; ++k) {
            wa[k] = wra[k]; ssa += wa[k] * wa[k];
            wg[k] = wrg[k]; ssg += wg[k] * wg[k];
        }
        float ma = mod2[(bfull * 128 + oc) * 64 + u * 8 + v];
        float mg = mod2[(bfull * 128 + oc + 64) * 64 + u * 8 + v];
        float rna = ma * rsqrtf(fmaxf(ma * ma * ssa, 1e-30f));
        float rng = mg * rsqrtf(fmaxf(mg * mg * ssg, 1e-30f));
#pragma unroll
        for (int k = 0; k < 9; ++k) { wa[k] *= rna; wg[k] *= rng; }
    }
    const float ba = b2[oc], bg = b2[oc + 64];

    const unsigned short* pa = t1 + (((size_t)z * 128 + oc) << 16);
    const unsigned short* pg = pa + ((size_t)64 << 16);

    float fa[3][8], fg[3][8], la[3], ra[3], lg[3], rg[3];
#pragma unroll
    for (int dr = 0; dr < 3; ++dr) {
        int rr = row - 1 + dr;
        if (rr >= 0 && rr < 256) {
            u16x8 va = *(const u16x8*)&pa[rr * 256 + strip * 8];
            u16x8 vg = *(const u16x8*)&pg[rr * 256 + strip * 8];
#pragma unroll
            for (int e = 0; e < 8; ++e) { fa[dr][e] = b2f(va[e]); fg[dr][e] = b2f(vg[e]); }
        } else {
#pragma unroll
            for (int e = 0; e < 8; ++e) { fa[dr][e] = 0.f; fg[dr][e] = 0.f; }
        }
        float t;
        t = __shfl_up(fa[dr][7], 1);   la[dr] = (strip == 0)  ? 0.f : t;
        t = __shfl_up(fg[dr][7], 1);   lg[dr] = (strip == 0)  ? 0.f : t;
        t = __shfl_down(fa[dr][0], 1); ra[dr] = (strip == 31) ? 0.f : t;
        t = __shfl_down(fg[dr][0], 1); rg[dr] = (strip == 31) ? 0.f : t;
    }

    float psum = 0.f;
    u16x8 pk;
#pragma unroll
    for (int j = 0; j < 8; ++j) {
        float a = 0.f, g = 0.f;
#pragma unroll
        for (int dr = 0; dr < 3; ++dr) {
            float m1a = (j == 0) ? la[dr] : fa[dr][j - 1];
            float p1a = (j == 7) ? ra[dr] : fa[dr][j + 1];
            float m1g = (j == 0) ? lg[dr] : fg[dr][j - 1];
            float p1g = (j == 7) ? rg[dr] : fg[dr][j + 1];
            a += wa[dr * 3] * m1a + wa[dr * 3 + 1] * fa[dr][j] + wa[dr * 3 + 2] * p1a;
            g += wg[dr * 3] * m1g + wg[dr * 3 + 1] * fg[dr][j] + wg[dr * 3 + 2] * p1g;
        }
        float val = (a + ba) * (g + bg);
        psum += val;
        pk[j] = f2b(val);
    }
    *(u16x8*)&t3[(((size_t)z * 64 + oc) << 16) + row * 256 + strip * 8] = pk;

    for (int off = 32; off > 0; off >>= 1) psum += __shfl_down(psum, off, 64);
    if ((tid & 63) == 0) wred[tid >> 6] = psum;
    __syncthreads();
    if (tid == 0)
        atomicAdd(&s0[bfull * 64 + oc], wred[0] + wred[1] + wred[2] + wred[3]);
}

// ---------------------------------------------------------------------------
extern "C" void kernel_launch(void* const* d_in, const int* in_sizes, int n_in,
                              void* d_out, int out_size, void* d_ws, size_t ws_size,
                              hipStream_t stream) {
    (void)in_sizes; (void)n_in; (void)out_size;
    const float* x    = (const float*)d_in[0];
    const float* w1   = (const float*)d_in[1];
    const float* b1   = (const float*)d_in[2];
    const float* w2   = (const float*)d_in[3];
    const float* b2   = (const float*)d_in[4];
    const float* w3   = (const float*)d_in[5];
    const float* b3   = (const float*)d_in[6];
    const float* scaw = (const float*)d_in[7];
    const float* scab = (const float*)d_in[8];
    const float* w4   = (const float*)d_in[9];
    const float* b4   = (const float*)d_in[10];
    const float* w5   = (const float*)d_in[11];
    const float* b5   = (const float*)d_in[12];
    const float* n1w  = (const float*)d_in[13];
    const float* n1b  = (const float*)d_in[14];
    const float* n2w  = (const float*)d_in[15];
    const float* n2b  = (const float*)d_in[16];
    const float* beta = (const float*)d_in[17];
    const float* gam  = (const float*)d_in[18];
    const float* mod1 = (const float*)d_in[19];
    const float* mod2 = (const float*)d_in[20];
    const float* mod3 = (const float*)d_in[21];
    const float* mod4 = (const float*)d_in[22];
    const float* mod5 = (const float*)d_in[23];

    char* ws = (char*)d_ws;
    float* outf = (float*)d_out;

    const size_t IMGel = (size_t)64 * 65536;
    const size_t T1B   = (size_t)128 * 65536 * 2;   // 16.78 MB per batch
    const size_t T3B   = (size_t)64 * 65536 * 2;    // 8.39 MB per batch
    const size_t PW1B = 2097152, PW3B = 1048576, PW4B = 2097152, PW5B = 1048576;
    const size_t TBLB = PW1B + PW3B + PW4B + PW5B;  // 6.29 MB

    const size_t needA = 2 * (T1B + T3B) + 4096 + TBLB;   // ~56.6 MB
    const bool planA = ws_size >= needA;                  // ws measured ~268 MB
    const size_t NBT = planA ? 2 : 1;

    unsigned short* t1 = (unsigned short*)ws;
    unsigned short* t3 = (unsigned short*)(ws + NBT * T1B);
    char* statb = ws + NBT * (T1B + T3B);
    float* s0   = (float*)statb;
    unsigned short* pw1 = (unsigned short*)(statb + 4096);
    unsigned short* pw3 = (unsigned short*)(statb + 4096 + PW1B);
    unsigned short* pw4 = (unsigned short*)(statb + 4096 + PW1B + PW3B);
    unsigned short* pw5 = (unsigned short*)(statb + 4096 + PW1B + PW3B + PW4B);

    dim3 blk(256);

    prep_k<<<768, blk, 0, stream>>>(w1, mod1, w3, mod3, beta, w4, mod4,
                                    w5, mod5, gam, pw1, pw3, pw4, pw5, s0);

    if (planA) {
        dim3 gconv(64, 8, 2), gdw(64, 32, 2);
        head_k<<<gconv, blk, 0, stream>>>(x, t1, pw1, b1, n1w, n1b, 0);
        dw_k<<<gdw, blk, 0, stream>>>(t1, t3, w2, b2, mod2, s0, 0);
        tail_k<<<gconv, blk, 0, stream>>>(t3, x, outf, pw3, b3, beta,
                                          pw4, b4, n2w, n2b, pw5, b5, gam,
                                          scaw, scab, s0, 0);
    } else {
        for (int bb = 0; bb < 2; ++bb) {
            const float* x_b   = x    + (size_t)bb * IMGel;
            float*       out_b = outf + (size_t)bb * IMGel;
            dim3 gconv(64, 8, 1), gdw(64, 32, 1);
            head_k<<<gconv, blk, 0, stream>>>(x_b, t1, pw1, b1, n1w, n1b, bb);
            dw_k<<<gdw, blk, 0, stream>>>(t1, t3, w2, b2, mod2, s0, bb);
            tail_k<<<gconv, blk, 0, stream>>>(t3, x_b, out_b, pw3, b3, beta,
                                              pw4, b4, n2w, n2b, pw5, b5, gam,
                                              scaw, scab, s0, bb);
        }
    }
}